// Round 7
// baseline (121.171 us; speedup 1.0000x reference)
//
#include <hip/hip_runtime.h>
#include <hip/hip_bf16.h>
#include <math.h>

#define MUL 8
#define HID 16
#define NB 10

typedef short short8 __attribute__((ext_vector_type(8)));
typedef float floatx4 __attribute__((ext_vector_type(4)));

__device__ __forceinline__ unsigned short f2bf_u(float x) {
    unsigned u = __float_as_uint(x);
    return (unsigned short)((u + 0x7fffu + ((u >> 16) & 1u)) >> 16);  // RNE
}
__device__ __forceinline__ short f2bf(float x) { return (short)f2bf_u(x); }

__device__ __forceinline__ unsigned pack2(float lo, float hi) {
#if __has_builtin(__builtin_amdgcn_cvt_pk_bf16_f32)
    typedef __bf16 bf2 __attribute__((ext_vector_type(2)));
    bf2 p = __builtin_amdgcn_cvt_pk_bf16_f32(lo, hi);
    return *reinterpret_cast<unsigned*>(&p);
#else
    return (unsigned)f2bf_u(lo) | ((unsigned)f2bf_u(hi) << 16);
#endif
}

#define UNP(u, lo, hi) { lo = __uint_as_float((u) << 16); hi = __uint_as_float((u) & 0xffff0000u); }

// ws layout (floats): [0..511] W2r scaled | [512..671] W1s | Xb @ byte 2688
// Kernel 1: bf16-pack the node table (6.4 -> 3.2 MB, ~L2-resident); block 0
// additionally builds scaled weights and zeroes out[0].
__global__ __launch_bounds__(256) void conv_prep_kernel(
    const float* __restrict__ X, unsigned* __restrict__ Xb, int nPack,
    const float* __restrict__ W1, const float* __restrict__ W2,
    float* __restrict__ ws, float* __restrict__ out)
{
    int i = blockIdx.x * 256 + threadIdx.x;
    if (i < nPack) {
        float2 f = ((const float2*)X)[i];
        Xb[i] = pack2(f.x, f.y);
    }
    if (blockIdx.x == 0) {
        int t = threadIdx.x;
        if (t == 0) out[0] = 0.0f;
        const float pw0 = 0.25f;            // sqrt(1/16)
        const float pw1 = 0.43301270189f;   // sqrt(3/16)
        const float i3  = 0.57735026919f;   // 1/sqrt(3)
#pragma unroll
        for (int k = t; k < HID * 32; k += 256) {
            int j  = k >> 5;
            int cu = k & 31;
            int c  = cu >> 3;
            float gs = (c < 2) ? pw0 : ((c == 2) ? pw1 : pw1 * i3);
            const float* p = W2 + j * 256 + cu * 8;
            float s = 0.0f;
#pragma unroll
            for (int v = 0; v < 8; ++v) s += p[v];
            ws[k] = s * 0.0625f * gs;       // 1/sqrt(HID) * 1/sqrt(NUM_NEIGHBORS)
        }
        if (t < NB * HID) ws[512 + t] = W1[t] * 1.41421356237f;
    }
}

// Kernel 2 (R5 structure — best measured): each wave handles 64 edges, one
// per lane. Per-lane h[16] + f[32] features; transpose through XOR-swizzled
// LDS into MFMA fragments; M += h x f via 4 MFMAs (K=64); weights applied
// ONCE per wave in the epilogue (no per-edge weight loads).
__global__ __launch_bounds__(256, 4) void edge_kernel(
    const unsigned* __restrict__ Xb,   // N x 16 uints (32 bf16)
    const float* __restrict__ EV,      // E x 3
    const int*   __restrict__ SRC,     // E
    const float* __restrict__ W2r,     // 16 x 32 scaled
    const float* __restrict__ W1s,     // 10 x 16 scaled
    float* __restrict__ out, int E)
{
    __shared__ short A_lds[4][16][64];  // [wave][j][kk]  (xor-swizzled units)
    __shared__ short B_lds[4][32][64];  // [wave][n][kk]
    int tid = threadIdx.x;
    int w = tid >> 6, l = tid & 63;
    int e0 = blockIdx.x * 256 + tid;
    bool valid = (e0 < E);
    int e = valid ? e0 : 0;

    int   si = __builtin_nontemporal_load(SRC + e);
    float ex = __builtin_nontemporal_load(EV + 3 * e);
    float ey = __builtin_nontemporal_load(EV + 3 * e + 1);
    float ez = __builtin_nontemporal_load(EV + 3 * e + 2);
    const uint4* xp = (const uint4*)(Xb + (size_t)si * 16);
    uint4 q0 = xp[0], q1 = xp[1], q2 = xp[2], q3 = xp[3];

    float r = sqrtf(ex * ex + ey * ey + ez * ez);
    float ir = 1.0f / r;
    float ux = ex * ir, uy = ey * ir, uz = ez * ir;
    float U = ux + uy + uz;

    // 2-sparse soft one-hot -> h (masked to 0 for invalid lanes)
    const float inv_step = 11.0f / 3.0f;
    float qq = r * inv_step;
    int qi = (int)floorf(qq);
    int ia = qi - 1, ib = qi;
    float diffa = qq - (float)(ia + 1);
    float diffb = qq - (float)(ib + 1);
    float dena = 1.0f - diffa * diffa;
    float denb = 1.0f - diffb * diffb;
    bool va = (ia >= 0) & (ia < NB) & valid;
    bool vb = (ib >= 0) & (ib < NB) & valid;
    float fa = va ? 1.14136f * __expf(2.0f - 2.0f / dena) : 0.0f;
    float fb = vb ? 1.14136f * __expf(2.0f - 2.0f / denb) : 0.0f;
    int ica = min(max(ia, 0), NB - 1);
    int icb = min(max(ib, 0), NB - 1);
    const float4* ra4 = (const float4*)(W1s + ica * HID);
    const float4* rb4 = (const float4*)(W1s + icb * HID);

    // write A column (this lane's edge): A[j][kk=l], swizzled
#pragma unroll
    for (int k4 = 0; k4 < 4; ++k4) {
        float4 wa = ra4[k4], wb = rb4[k4];
        float aj[4] = {fa * wa.x + fb * wb.x, fa * wa.y + fb * wb.y,
                       fa * wa.z + fb * wb.z, fa * wa.w + fb * wb.w};
#pragma unroll
        for (int jj = 0; jj < 4; ++jj) {
            int j = 4 * k4 + jj;
            float hj = (aj[jj] > 0.0f) ? aj[jj] : 0.0f;
            A_lds[w][j][((((l >> 3) ^ (j & 7)) << 3) | (l & 7))] = f2bf(hj);
        }
    }

    // features: f[0..7]=s (exact bf16 bits), f[8..15]=d, f[16..23]=s*U, f[24..31]=V
    float s[8], vv[24];
    UNP(q0.x, s[0], s[1]); UNP(q0.y, s[2], s[3]);
    UNP(q0.z, s[4], s[5]); UNP(q0.w, s[6], s[7]);
    UNP(q1.x, vv[0], vv[1]);   UNP(q1.y, vv[2], vv[3]);
    UNP(q1.z, vv[4], vv[5]);   UNP(q1.w, vv[6], vv[7]);
    UNP(q2.x, vv[8], vv[9]);   UNP(q2.y, vv[10], vv[11]);
    UNP(q2.z, vv[12], vv[13]); UNP(q2.w, vv[14], vv[15]);
    UNP(q3.x, vv[16], vv[17]); UNP(q3.y, vv[18], vv[19]);
    UNP(q3.z, vv[20], vv[21]); UNP(q3.w, vv[22], vv[23]);

    unsigned sq[4] = {q0.x, q0.y, q0.z, q0.w};
#pragma unroll
    for (int u = 0; u < 8; ++u) {
        unsigned bits = (u & 1) ? (sq[u >> 1] >> 16) : (sq[u >> 1] & 0xffffu);
        B_lds[w][u][((((l >> 3) ^ (u & 7)) << 3) | (l & 7))] = (short)bits;
    }
#pragma unroll
    for (int u = 0; u < 8; ++u) {
        float vx = vv[3 * u], vy = vv[3 * u + 1], vz = vv[3 * u + 2];
        float d = vx * ux + vy * uy + vz * uz;
        float V = vx + vy + vz;
        int n1 = 8 + u, n2 = 16 + u, n3 = 24 + u;
        B_lds[w][n1][((((l >> 3) ^ (n1 & 7)) << 3) | (l & 7))] = f2bf(d);
        B_lds[w][n2][((((l >> 3) ^ (n2 & 7)) << 3) | (l & 7))] = f2bf(s[u] * U);
        B_lds[w][n3][((((l >> 3) ^ (n3 & 7)) << 3) | (l & 7))] = f2bf(V);
    }
    __syncthreads();

    // fragments: A[m=ln][k=c*8..], B[k][n=ln or ln+16]
    int ln = l & 15, q = l >> 4;
    short8 a0  = *(const short8*)&A_lds[w][ln][(((q)     ^ (ln & 7)) << 3)];
    short8 a1  = *(const short8*)&A_lds[w][ln][(((4 + q) ^ (ln & 7)) << 3)];
    short8 b00 = *(const short8*)&B_lds[w][ln][(((q)     ^ (ln & 7)) << 3)];
    short8 b01 = *(const short8*)&B_lds[w][ln + 16][(((q)     ^ (ln & 7)) << 3)];
    short8 b10 = *(const short8*)&B_lds[w][ln][(((4 + q) ^ (ln & 7)) << 3)];
    short8 b11 = *(const short8*)&B_lds[w][ln + 16][(((4 + q) ^ (ln & 7)) << 3)];

    floatx4 acc0 = {0.f, 0.f, 0.f, 0.f}, acc1 = {0.f, 0.f, 0.f, 0.f};
    acc0 = __builtin_amdgcn_mfma_f32_16x16x32_bf16(a0, b00, acc0, 0, 0, 0);
    acc1 = __builtin_amdgcn_mfma_f32_16x16x32_bf16(a0, b01, acc1, 0, 0, 0);
    acc0 = __builtin_amdgcn_mfma_f32_16x16x32_bf16(a1, b10, acc0, 0, 0, 0);
    acc1 = __builtin_amdgcn_mfma_f32_16x16x32_bf16(a1, b11, acc1, 0, 0, 0);

    // epilogue: elementwise W . M once per wave.
    // C/D: col = lane&15 (=n), row = (lane>>4)*4 + reg  (m89-verified)
    float p = 0.0f;
#pragma unroll
    for (int i = 0; i < 4; ++i) {
        int row = q * 4 + i;
        p += acc0[i] * W2r[row * 32 + ln] + acc1[i] * W2r[row * 32 + 16 + ln];
    }
#pragma unroll
    for (int off = 32; off > 0; off >>= 1)
        p += __shfl_down(p, off, 64);

    __shared__ float wsum[4];
    if (l == 0) wsum[w] = p;
    __syncthreads();
    if (tid == 0)
        atomicAdd(out, wsum[0] + wsum[1] + wsum[2] + wsum[3]);
}

// Fallback (ws too small for bf16 table): per-edge f32 contraction.
__global__ __launch_bounds__(256, 6) void edge_kernel_f32(
    const float* __restrict__ X, const float* __restrict__ EV,
    const int* __restrict__ SRC, const float* __restrict__ W2r,
    const float* __restrict__ W1s, float* __restrict__ out, int E)
{
    int tid = threadIdx.x;
    int e = blockIdx.x * 256 + tid;
    float contrib = 0.0f;
    if (e < E) {
        int si = SRC[e];
        const float4* xp = (const float4*)(X + (size_t)si * 32);
        float4 x[8];
#pragma unroll
        for (int k = 0; k < 8; ++k) x[k] = xp[k];
        float ex = EV[3 * e], ey = EV[3 * e + 1], ez = EV[3 * e + 2];
        float r = sqrtf(ex * ex + ey * ey + ez * ez);
        float ir = 1.0f / r;
        float ux = ex * ir, uy = ey * ir, uz = ez * ir;
        float U = ux + uy + uz;
        const float inv_step = 11.0f / 3.0f;
        float qq = r * inv_step;
        int qi = (int)floorf(qq);
        int ia = qi - 1, ib = qi;
        float diffa = qq - (float)(ia + 1), diffb = qq - (float)(ib + 1);
        float dena = 1.0f - diffa * diffa, denb = 1.0f - diffb * diffb;
        float fa = ((ia >= 0) & (ia < NB)) ? 1.14136f * __expf(2.0f - 2.0f / dena) : 0.0f;
        float fb = ((ib >= 0) & (ib < NB)) ? 1.14136f * __expf(2.0f - 2.0f / denb) : 0.0f;
        const float* ra = W1s + min(max(ia, 0), NB - 1) * HID;
        const float* rb = W1s + min(max(ib, 0), NB - 1) * HID;
        float h[HID];
#pragma unroll
        for (int j = 0; j < HID; ++j) {
            float a = fa * ra[j] + fb * rb[j];
            h[j] = (a > 0.0f) ? a : 0.0f;
        }
        float s[8] = {x[0].x, x[0].y, x[0].z, x[0].w, x[1].x, x[1].y, x[1].z, x[1].w};
        float vv[24];
#pragma unroll
        for (int k = 0; k < 6; ++k) {
            vv[4 * k + 0] = x[2 + k].x; vv[4 * k + 1] = x[2 + k].y;
            vv[4 * k + 2] = x[2 + k].z; vv[4 * k + 3] = x[2 + k].w;
        }
        float d[8], V[8];
#pragma unroll
        for (int u = 0; u < 8; ++u) {
            float vx = vv[3 * u], vy = vv[3 * u + 1], vz = vv[3 * u + 2];
            d[u] = vx * ux + vy * uy + vz * uz;
            V[u] = vx + vy + vz;
        }
        float acc = 0.0f;
#pragma unroll
        for (int j = 0; j < HID; ++j) {
            const float* wt = W2r + j * 32;
            float A = 0, B = 0, C = 0, D = 0;
#pragma unroll
            for (int u = 0; u < 8; ++u) {
                A += wt[u] * s[u]; B += wt[8 + u] * d[u];
                C += wt[16 + u] * s[u]; D += wt[24 + u] * V[u];
            }
            acc += h[j] * (A + B + U * C + D);
        }
        contrib = acc;
    }
#pragma unroll
    for (int off = 32; off > 0; off >>= 1)
        contrib += __shfl_down(contrib, off, 64);
    __shared__ float wsum[4];
    int lane = tid & 63, w = tid >> 6;
    if (lane == 0) wsum[w] = contrib;
    __syncthreads();
    if (tid == 0)
        atomicAdd(out, wsum[0] + wsum[1] + wsum[2] + wsum[3]);
}

extern "C" void kernel_launch(void* const* d_in, const int* in_sizes, int n_in,
                              void* d_out, int out_size, void* d_ws, size_t ws_size,
                              hipStream_t stream) {
    const float* X   = (const float*)d_in[0];
    const float* EV  = (const float*)d_in[1];
    const float* W1  = (const float*)d_in[2];
    const float* W2  = (const float*)d_in[3];
    const int*   SRC = (const int*)d_in[4];
    int E = in_sizes[4];
    int N = in_sizes[0] / 32;

    float* ws  = (float*)d_ws;
    float* out = (float*)d_out;

    size_t need = 2688 + (size_t)N * 64;
    if (ws_size >= need) {
        unsigned* Xb = (unsigned*)((char*)d_ws + 2688);
        int nPack = N * 16;
        int cblocks = (nPack + 255) / 256;
        conv_prep_kernel<<<cblocks, 256, 0, stream>>>(X, Xb, nPack, W1, W2, ws, out);
        int eblocks = (E + 255) / 256;
        edge_kernel<<<eblocks, 256, 0, stream>>>(Xb, EV, SRC, ws, ws + 512, out, E);
    } else {
        conv_prep_kernel<<<1, 256, 0, stream>>>(X, (unsigned*)nullptr, 0, W1, W2, ws, out);
        int blocks = (E + 255) / 256;
        edge_kernel_f32<<<blocks, 256, 0, stream>>>(X, EV, SRC, ws, ws + 512, out, E);
    }
}

// Round 8
// 116.131 us; speedup vs baseline: 1.0434x; 1.0434x over previous
//
#include <hip/hip_runtime.h>
#include <hip/hip_bf16.h>
#include <math.h>

#define MUL 8
#define HID 16
#define NB 10

typedef short short8 __attribute__((ext_vector_type(8)));
typedef float floatx4 __attribute__((ext_vector_type(4)));

__device__ __forceinline__ unsigned short f2bf_u(float x) {
    unsigned u = __float_as_uint(x);
    return (unsigned short)((u + 0x7fffu + ((u >> 16) & 1u)) >> 16);  // RNE
}
__device__ __forceinline__ short f2bf(float x) { return (short)f2bf_u(x); }

__device__ __forceinline__ unsigned pack2(float lo, float hi) {
#if __has_builtin(__builtin_amdgcn_cvt_pk_bf16_f32)
    typedef __bf16 bf2 __attribute__((ext_vector_type(2)));
    bf2 p = __builtin_amdgcn_cvt_pk_bf16_f32(lo, hi);
    return *reinterpret_cast<unsigned*>(&p);
#else
    return (unsigned)f2bf_u(lo) | ((unsigned)f2bf_u(hi) << 16);
#endif
}

#define UNP(u, lo, hi) { lo = __uint_as_float((u) << 16); hi = __uint_as_float((u) & 0xffff0000u); }

// ws layout: [0..511] W2r | [512..671] W1s | [672..735] partial(64)
// | Xb @ byte 4096 (N*16 uints) | Xg @ byte XG_OFF (E*16 uints)
// Kernel 1: bf16-pack node table; block 0 builds scaled weights + zeroes partials.
__global__ __launch_bounds__(256) void conv_prep_kernel(
    const float* __restrict__ X, unsigned* __restrict__ Xb, int nPack,
    const float* __restrict__ W1, const float* __restrict__ W2,
    float* __restrict__ ws)
{
    int i = blockIdx.x * 256 + threadIdx.x;
    if (i < nPack) {
        float2 f = ((const float2*)X)[i];
        Xb[i] = pack2(f.x, f.y);
    }
    if (blockIdx.x == 0) {
        int t = threadIdx.x;
        if (t < 64) ws[672 + t] = 0.0f;
        const float pw0 = 0.25f;            // sqrt(1/16)
        const float pw1 = 0.43301270189f;   // sqrt(3/16)
        const float i3  = 0.57735026919f;   // 1/sqrt(3)
#pragma unroll
        for (int k = t; k < HID * 32; k += 256) {
            int j  = k >> 5;
            int cu = k & 31;
            int c  = cu >> 3;
            float gs = (c < 2) ? pw0 : ((c == 2) ? pw1 : pw1 * i3);
            const float* p = W2 + j * 256 + cu * 8;
            float s = 0.0f;
#pragma unroll
            for (int v = 0; v < 8; ++v) s += p[v];
            ws[k] = s * 0.0625f * gs;       // 1/sqrt(HID) * 1/sqrt(NUM_NEIGHBORS)
        }
        if (t < NB * HID) ws[512 + t] = W1[t] * 1.41421356237f;
    }
}

// Kernel 2 — PURE GATHER: Xg[e] = Xb[SRC[e]] (64 B/edge). Tiny register
// state, no LDS, no barrier -> max resident waves keep the L1 MSHRs full.
// This isolates the divergent-gather latency wall from all compute.
__global__ __launch_bounds__(256) void gather_kernel(
    const unsigned* __restrict__ Xb, const int* __restrict__ SRC,
    uint4* __restrict__ Xg, int E)
{
    int e = blockIdx.x * 256 + threadIdx.x;
    if (e < E) {
        int si = SRC[e];
        const uint4* sp = (const uint4*)(Xb + (size_t)si * 16);
        uint4 a = sp[0], b = sp[1], c = sp[2], d = sp[3];
        uint4* dp = Xg + (size_t)e * 4;
        dp[0] = a; dp[1] = b; dp[2] = c; dp[3] = d;
    }
}

// Kernel 3 — COMPUTE (R5 structure): one edge/lane, sequential coalesced
// reads from Xg; transpose through XOR-swizzled LDS; M += h x f via 4 MFMAs;
// weights applied once per wave in the epilogue; partial-array reduction.
__global__ __launch_bounds__(256, 4) void compute_kernel(
    const uint4* __restrict__ Xg,      // E x 4 uint4 (32 bf16/edge, by edge)
    const float* __restrict__ EV,      // E x 3
    const float* __restrict__ W2r,     // 16 x 32 scaled
    const float* __restrict__ W1s,     // 10 x 16 scaled
    float* __restrict__ partial, int E)
{
    __shared__ short A_lds[4][16][64];  // [wave][j][kk]  (xor-swizzled)
    __shared__ short B_lds[4][32][64];  // [wave][n][kk]
    int tid = threadIdx.x;
    int w = tid >> 6, l = tid & 63;
    int e0 = blockIdx.x * 256 + tid;
    bool valid = (e0 < E);
    int e = valid ? e0 : (E - 1);

    const uint4* xp = Xg + (size_t)e * 4;
    uint4 q0 = xp[0], q1 = xp[1], q2 = xp[2], q3 = xp[3];
    float ex = EV[3 * e], ey = EV[3 * e + 1], ez = EV[3 * e + 2];

    float r = sqrtf(ex * ex + ey * ey + ez * ez);
    float ir = 1.0f / r;
    float ux = ex * ir, uy = ey * ir, uz = ez * ir;
    float U = ux + uy + uz;

    // 2-sparse soft one-hot -> h (zeroed for invalid lanes)
    const float inv_step = 11.0f / 3.0f;
    float qq = r * inv_step;
    int qi = (int)floorf(qq);
    int ia = qi - 1, ib = qi;
    float diffa = qq - (float)(ia + 1);
    float diffb = qq - (float)(ib + 1);
    float dena = 1.0f - diffa * diffa;
    float denb = 1.0f - diffb * diffb;
    bool va = (ia >= 0) & (ia < NB) & valid;
    bool vb = (ib >= 0) & (ib < NB) & valid;
    float fa = va ? 1.14136f * __expf(2.0f - 2.0f / dena) : 0.0f;
    float fb = vb ? 1.14136f * __expf(2.0f - 2.0f / denb) : 0.0f;
    int ica = min(max(ia, 0), NB - 1);
    int icb = min(max(ib, 0), NB - 1);
    const float4* ra4 = (const float4*)(W1s + ica * HID);
    const float4* rb4 = (const float4*)(W1s + icb * HID);

#pragma unroll
    for (int k4 = 0; k4 < 4; ++k4) {
        float4 wa = ra4[k4], wb = rb4[k4];
        float aj[4] = {fa * wa.x + fb * wb.x, fa * wa.y + fb * wb.y,
                       fa * wa.z + fb * wb.z, fa * wa.w + fb * wb.w};
#pragma unroll
        for (int jj = 0; jj < 4; ++jj) {
            int j = 4 * k4 + jj;
            float hj = (aj[jj] > 0.0f) ? aj[jj] : 0.0f;
            A_lds[w][j][((((l >> 3) ^ (j & 7)) << 3) | (l & 7))] = f2bf(hj);
        }
    }

    // features: f[0..7]=s (raw bf16 bits), f[8..15]=d, f[16..23]=s*U, f[24..31]=V
    float s[8], vv[24];
    UNP(q0.x, s[0], s[1]); UNP(q0.y, s[2], s[3]);
    UNP(q0.z, s[4], s[5]); UNP(q0.w, s[6], s[7]);
    UNP(q1.x, vv[0], vv[1]);   UNP(q1.y, vv[2], vv[3]);
    UNP(q1.z, vv[4], vv[5]);   UNP(q1.w, vv[6], vv[7]);
    UNP(q2.x, vv[8], vv[9]);   UNP(q2.y, vv[10], vv[11]);
    UNP(q2.z, vv[12], vv[13]); UNP(q2.w, vv[14], vv[15]);
    UNP(q3.x, vv[16], vv[17]); UNP(q3.y, vv[18], vv[19]);
    UNP(q3.z, vv[20], vv[21]); UNP(q3.w, vv[22], vv[23]);

    unsigned sq[4] = {q0.x, q0.y, q0.z, q0.w};
#pragma unroll
    for (int u = 0; u < 8; ++u) {
        unsigned bits = (u & 1) ? (sq[u >> 1] >> 16) : (sq[u >> 1] & 0xffffu);
        B_lds[w][u][((((l >> 3) ^ (u & 7)) << 3) | (l & 7))] = (short)bits;
    }
#pragma unroll
    for (int u = 0; u < 8; ++u) {
        float vx = vv[3 * u], vy = vv[3 * u + 1], vz = vv[3 * u + 2];
        float d = vx * ux + vy * uy + vz * uz;
        float V = vx + vy + vz;
        int n1 = 8 + u, n2 = 16 + u, n3 = 24 + u;
        B_lds[w][n1][((((l >> 3) ^ (n1 & 7)) << 3) | (l & 7))] = f2bf(d);
        B_lds[w][n2][((((l >> 3) ^ (n2 & 7)) << 3) | (l & 7))] = f2bf(s[u] * U);
        B_lds[w][n3][((((l >> 3) ^ (n3 & 7)) << 3) | (l & 7))] = f2bf(V);
    }
    __syncthreads();

    int ln = l & 15, q = l >> 4;
    short8 a0  = *(const short8*)&A_lds[w][ln][(((q)     ^ (ln & 7)) << 3)];
    short8 a1  = *(const short8*)&A_lds[w][ln][(((4 + q) ^ (ln & 7)) << 3)];
    short8 b00 = *(const short8*)&B_lds[w][ln][(((q)     ^ (ln & 7)) << 3)];
    short8 b01 = *(const short8*)&B_lds[w][ln + 16][(((q)     ^ (ln & 7)) << 3)];
    short8 b10 = *(const short8*)&B_lds[w][ln][(((4 + q) ^ (ln & 7)) << 3)];
    short8 b11 = *(const short8*)&B_lds[w][ln + 16][(((4 + q) ^ (ln & 7)) << 3)];

    floatx4 acc0 = {0.f, 0.f, 0.f, 0.f}, acc1 = {0.f, 0.f, 0.f, 0.f};
    acc0 = __builtin_amdgcn_mfma_f32_16x16x32_bf16(a0, b00, acc0, 0, 0, 0);
    acc1 = __builtin_amdgcn_mfma_f32_16x16x32_bf16(a0, b01, acc1, 0, 0, 0);
    acc0 = __builtin_amdgcn_mfma_f32_16x16x32_bf16(a1, b10, acc0, 0, 0, 0);
    acc1 = __builtin_amdgcn_mfma_f32_16x16x32_bf16(a1, b11, acc1, 0, 0, 0);

    // epilogue: elementwise W . M once per wave.
    // C/D: col = lane&15 (=n), row = (lane>>4)*4 + reg  (m89-verified)
    float p = 0.0f;
#pragma unroll
    for (int i = 0; i < 4; ++i) {
        int row = q * 4 + i;
        p += acc0[i] * W2r[row * 32 + ln] + acc1[i] * W2r[row * 32 + 16 + ln];
    }
#pragma unroll
    for (int off = 32; off > 0; off >>= 1)
        p += __shfl_down(p, off, 64);

    __shared__ float wsum[4];
    if (l == 0) wsum[w] = p;
    __syncthreads();
    if (tid == 0)
        atomicAdd(partial + (blockIdx.x & 63), wsum[0] + wsum[1] + wsum[2] + wsum[3]);
}

__global__ void final_kernel(const float* __restrict__ partial,
                             float* __restrict__ out) {
    int t = threadIdx.x;  // 64
    float v = partial[t];
#pragma unroll
    for (int off = 32; off > 0; off >>= 1)
        v += __shfl_down(v, off, 64);
    if (t == 0) out[0] = v;
}

// Fallback (ws too small): per-edge f32 contraction, atomic to partial.
__global__ __launch_bounds__(256, 6) void edge_kernel_f32(
    const float* __restrict__ X, const float* __restrict__ EV,
    const int* __restrict__ SRC, const float* __restrict__ W2r,
    const float* __restrict__ W1s, float* __restrict__ partial, int E)
{
    int tid = threadIdx.x;
    int e = blockIdx.x * 256 + tid;
    float contrib = 0.0f;
    if (e < E) {
        int si = SRC[e];
        const float4* xp = (const float4*)(X + (size_t)si * 32);
        float4 x[8];
#pragma unroll
        for (int k = 0; k < 8; ++k) x[k] = xp[k];
        float ex = EV[3 * e], ey = EV[3 * e + 1], ez = EV[3 * e + 2];
        float r = sqrtf(ex * ex + ey * ey + ez * ez);
        float ir = 1.0f / r;
        float ux = ex * ir, uy = ey * ir, uz = ez * ir;
        float U = ux + uy + uz;
        const float inv_step = 11.0f / 3.0f;
        float qq = r * inv_step;
        int qi = (int)floorf(qq);
        int ia = qi - 1, ib = qi;
        float diffa = qq - (float)(ia + 1), diffb = qq - (float)(ib + 1);
        float dena = 1.0f - diffa * diffa, denb = 1.0f - diffb * diffb;
        float fa = ((ia >= 0) & (ia < NB)) ? 1.14136f * __expf(2.0f - 2.0f / dena) : 0.0f;
        float fb = ((ib >= 0) & (ib < NB)) ? 1.14136f * __expf(2.0f - 2.0f / denb) : 0.0f;
        const float* ra = W1s + min(max(ia, 0), NB - 1) * HID;
        const float* rb = W1s + min(max(ib, 0), NB - 1) * HID;
        float h[HID];
#pragma unroll
        for (int j = 0; j < HID; ++j) {
            float a = fa * ra[j] + fb * rb[j];
            h[j] = (a > 0.0f) ? a : 0.0f;
        }
        float s[8] = {x[0].x, x[0].y, x[0].z, x[0].w, x[1].x, x[1].y, x[1].z, x[1].w};
        float vv[24];
#pragma unroll
        for (int k = 0; k < 6; ++k) {
            vv[4 * k + 0] = x[2 + k].x; vv[4 * k + 1] = x[2 + k].y;
            vv[4 * k + 2] = x[2 + k].z; vv[4 * k + 3] = x[2 + k].w;
        }
        float d[8], V[8];
#pragma unroll
        for (int u = 0; u < 8; ++u) {
            float vx = vv[3 * u], vy = vv[3 * u + 1], vz = vv[3 * u + 2];
            d[u] = vx * ux + vy * uy + vz * uz;
            V[u] = vx + vy + vz;
        }
        float acc = 0.0f;
#pragma unroll
        for (int j = 0; j < HID; ++j) {
            const float* wt = W2r + j * 32;
            float A = 0, B = 0, C = 0, D = 0;
#pragma unroll
            for (int u = 0; u < 8; ++u) {
                A += wt[u] * s[u]; B += wt[8 + u] * d[u];
                C += wt[16 + u] * s[u]; D += wt[24 + u] * V[u];
            }
            acc += h[j] * (A + B + U * C + D);
        }
        contrib = acc;
    }
#pragma unroll
    for (int off = 32; off > 0; off >>= 1)
        contrib += __shfl_down(contrib, off, 64);
    __shared__ float wsum[4];
    int lane = tid & 63, w = tid >> 6;
    if (lane == 0) wsum[w] = contrib;
    __syncthreads();
    if (tid == 0)
        atomicAdd(partial + (blockIdx.x & 63), wsum[0] + wsum[1] + wsum[2] + wsum[3]);
}

extern "C" void kernel_launch(void* const* d_in, const int* in_sizes, int n_in,
                              void* d_out, int out_size, void* d_ws, size_t ws_size,
                              hipStream_t stream) {
    const float* X   = (const float*)d_in[0];
    const float* EV  = (const float*)d_in[1];
    const float* W1  = (const float*)d_in[2];
    const float* W2  = (const float*)d_in[3];
    const int*   SRC = (const int*)d_in[4];
    int E = in_sizes[4];
    int N = in_sizes[0] / 32;

    float* ws      = (float*)d_ws;
    float* out     = (float*)d_out;
    float* partial = ws + 672;

    size_t xb_off = 4096;
    size_t xg_off = (xb_off + (size_t)N * 64 + 4095) & ~(size_t)4095;
    size_t need   = xg_off + (size_t)E * 64;

    int eblocks = (E + 255) / 256;
    if (ws_size >= need) {
        unsigned* Xb = (unsigned*)((char*)d_ws + xb_off);
        uint4*    Xg = (uint4*)((char*)d_ws + xg_off);
        int nPack = N * 16;
        conv_prep_kernel<<<(nPack + 255) / 256, 256, 0, stream>>>(X, Xb, nPack, W1, W2, ws);
        gather_kernel<<<eblocks, 256, 0, stream>>>(Xb, SRC, Xg, E);
        compute_kernel<<<eblocks, 256, 0, stream>>>(Xg, EV, ws, ws + 512, partial, E);
    } else {
        conv_prep_kernel<<<1, 256, 0, stream>>>(X, (unsigned*)nullptr, 0, W1, W2, ws);
        edge_kernel_f32<<<eblocks, 256, 0, stream>>>(X, EV, SRC, ws, ws + 512, partial, E);
    }
    final_kernel<<<1, 64, 0, stream>>>(partial, out);
}

// Round 9
// 96.303 us; speedup vs baseline: 1.2582x; 1.2059x over previous
//
#include <hip/hip_runtime.h>
#include <hip/hip_bf16.h>
#include <math.h>

#define MUL 8
#define HID 16
#define NB 10

typedef short short8 __attribute__((ext_vector_type(8)));
typedef float floatx4 __attribute__((ext_vector_type(4)));

__device__ __forceinline__ unsigned short f2bf_u(float x) {
    unsigned u = __float_as_uint(x);
    return (unsigned short)((u + 0x7fffu + ((u >> 16) & 1u)) >> 16);  // RNE
}
__device__ __forceinline__ short f2bf(float x) { return (short)f2bf_u(x); }

__device__ __forceinline__ unsigned pack2(float lo, float hi) {
#if __has_builtin(__builtin_amdgcn_cvt_pk_bf16_f32)
    typedef __bf16 bf2 __attribute__((ext_vector_type(2)));
    bf2 p = __builtin_amdgcn_cvt_pk_bf16_f32(lo, hi);
    return *reinterpret_cast<unsigned*>(&p);
#else
    return (unsigned)f2bf_u(lo) | ((unsigned)f2bf_u(hi) << 16);
#endif
}

#define UNP(u, lo, hi) { lo = __uint_as_float((u) << 16); hi = __uint_as_float((u) & 0xffff0000u); }

// ws layout (floats): [0..511] W2r | [512..671] W1s
// | partial slots @ ws[672 + k*16], k<64 (one 64B line per slot, independent
//   L2 RMW chains — single-address atomics measured +25 µs in R6/R7)
// | Xb @ byte 8192 (N x 16 uints)
__global__ __launch_bounds__(256) void conv_prep_kernel(
    const float* __restrict__ X, unsigned* __restrict__ Xb, int nPack,
    const float* __restrict__ W1, const float* __restrict__ W2,
    float* __restrict__ ws)
{
    int i = blockIdx.x * 256 + threadIdx.x;
    if (i < nPack) {
        float2 f = ((const float2*)X)[i];
        Xb[i] = pack2(f.x, f.y);
    }
    if (blockIdx.x == 0) {
        int t = threadIdx.x;
        if (t < 64) ws[672 + t * 16] = 0.0f;
        const float pw0 = 0.25f;            // sqrt(1/16)
        const float pw1 = 0.43301270189f;   // sqrt(3/16)
        const float i3  = 0.57735026919f;   // 1/sqrt(3)
#pragma unroll
        for (int k = t; k < HID * 32; k += 256) {
            int j  = k >> 5;
            int cu = k & 31;
            int c  = cu >> 3;
            float gs = (c < 2) ? pw0 : ((c == 2) ? pw1 : pw1 * i3);
            const float* p = W2 + j * 256 + cu * 8;
            float s = 0.0f;
#pragma unroll
            for (int v = 0; v < 8; ++v) s += p[v];
            ws[k] = s * 0.0625f * gs;       // 1/sqrt(HID) * 1/sqrt(NUM_NEIGHBORS)
        }
        if (t < NB * HID) ws[512 + t] = W1[t] * 1.41421356237f;
    }
}

// Edge kernel (R5 measured-best structure, barrier-free): one edge per lane,
// 64 edges per wave. Each wave owns its private LDS slice — same-wave DS
// ordering is program order (in-order DS pipe), so no __syncthreads needed;
// an lgkmcnt fence before the fragment reads is sufficient. Per-wave shuffle
// reduce + per-wave atomic into a line-spread partial slot.
__global__ __launch_bounds__(256, 4) void edge_kernel(
    const unsigned* __restrict__ Xb,   // N x 16 uints (32 bf16)
    const float* __restrict__ EV,      // E x 3
    const int*   __restrict__ SRC,     // E
    const float* __restrict__ W2r,     // 16 x 32 scaled
    const float* __restrict__ W1s,     // 10 x 16 scaled
    float* __restrict__ partial, int E)
{
    __shared__ short A_lds[4][16][64];  // [wave][j][kk]  (xor-swizzled)
    __shared__ short B_lds[4][32][64];  // [wave][n][kk]
    int tid = threadIdx.x;
    int w = tid >> 6, l = tid & 63;
    int e0 = blockIdx.x * 256 + tid;
    bool valid = (e0 < E);
    int e = valid ? e0 : 0;

    int   si = __builtin_nontemporal_load(SRC + e);
    float ex = __builtin_nontemporal_load(EV + 3 * e);
    float ey = __builtin_nontemporal_load(EV + 3 * e + 1);
    float ez = __builtin_nontemporal_load(EV + 3 * e + 2);
    const uint4* xp = (const uint4*)(Xb + (size_t)si * 16);
    uint4 q0 = xp[0], q1 = xp[1], q2 = xp[2], q3 = xp[3];

    float r = sqrtf(ex * ex + ey * ey + ez * ez);
    float ir = 1.0f / r;
    float ux = ex * ir, uy = ey * ir, uz = ez * ir;
    float U = ux + uy + uz;

    // 2-sparse soft one-hot -> h (masked to 0 for invalid lanes)
    const float inv_step = 11.0f / 3.0f;
    float qq = r * inv_step;
    int qi = (int)floorf(qq);
    int ia = qi - 1, ib = qi;
    float diffa = qq - (float)(ia + 1);
    float diffb = qq - (float)(ib + 1);
    float dena = 1.0f - diffa * diffa;
    float denb = 1.0f - diffb * diffb;
    bool va = (ia >= 0) & (ia < NB) & valid;
    bool vb = (ib >= 0) & (ib < NB) & valid;
    float fa = va ? 1.14136f * __expf(2.0f - 2.0f / dena) : 0.0f;
    float fb = vb ? 1.14136f * __expf(2.0f - 2.0f / denb) : 0.0f;
    int ica = min(max(ia, 0), NB - 1);
    int icb = min(max(ib, 0), NB - 1);
    const float* ra = W1s + ica * HID;
    const float* rb = W1s + icb * HID;

    // write A column (this lane's edge): A[j][kk=l], swizzled
#pragma unroll
    for (int j = 0; j < HID; ++j) {
        float a = fa * ra[j] + fb * rb[j];
        float hj = (a > 0.0f) ? a : 0.0f;
        A_lds[w][j][((((l >> 3) ^ (j & 7)) << 3) | (l & 7))] = f2bf(hj);
    }

    // features: f[0..7]=s (raw bf16 bits), f[8..15]=d, f[16..23]=s*U, f[24..31]=V
    float s[8], vv[24];
    UNP(q0.x, s[0], s[1]); UNP(q0.y, s[2], s[3]);
    UNP(q0.z, s[4], s[5]); UNP(q0.w, s[6], s[7]);
    UNP(q1.x, vv[0], vv[1]);   UNP(q1.y, vv[2], vv[3]);
    UNP(q1.z, vv[4], vv[5]);   UNP(q1.w, vv[6], vv[7]);
    UNP(q2.x, vv[8], vv[9]);   UNP(q2.y, vv[10], vv[11]);
    UNP(q2.z, vv[12], vv[13]); UNP(q2.w, vv[14], vv[15]);
    UNP(q3.x, vv[16], vv[17]); UNP(q3.y, vv[18], vv[19]);
    UNP(q3.z, vv[20], vv[21]); UNP(q3.w, vv[22], vv[23]);

    unsigned sq[4] = {q0.x, q0.y, q0.z, q0.w};
#pragma unroll
    for (int u = 0; u < 8; ++u) {
        unsigned bits = (u & 1) ? (sq[u >> 1] >> 16) : (sq[u >> 1] & 0xffffu);
        B_lds[w][u][((((l >> 3) ^ (u & 7)) << 3) | (l & 7))] = (short)bits;
    }
#pragma unroll
    for (int u = 0; u < 8; ++u) {
        float vx = vv[3 * u], vy = vv[3 * u + 1], vz = vv[3 * u + 2];
        float d = vx * ux + vy * uy + vz * uz;
        float V = vx + vy + vz;
        int n1 = 8 + u, n2 = 16 + u, n3 = 24 + u;
        B_lds[w][n1][((((l >> 3) ^ (n1 & 7)) << 3) | (l & 7))] = f2bf(d);
        B_lds[w][n2][((((l >> 3) ^ (n2 & 7)) << 3) | (l & 7))] = f2bf(s[u] * U);
        B_lds[w][n3][((((l >> 3) ^ (n3 & 7)) << 3) | (l & 7))] = f2bf(V);
    }

    // wave-local LDS transpose: same-wave ds_write -> ds_read is program-
    // ordered in the DS pipe; fence data + block compiler reordering.
    asm volatile("s_waitcnt lgkmcnt(0)" ::: "memory");

    int ln = l & 15, q = l >> 4;
    short8 a0  = *(const short8*)&A_lds[w][ln][(((q)     ^ (ln & 7)) << 3)];
    short8 a1  = *(const short8*)&A_lds[w][ln][(((4 + q) ^ (ln & 7)) << 3)];
    short8 b00 = *(const short8*)&B_lds[w][ln][(((q)     ^ (ln & 7)) << 3)];
    short8 b01 = *(const short8*)&B_lds[w][ln + 16][(((q)     ^ (ln & 7)) << 3)];
    short8 b10 = *(const short8*)&B_lds[w][ln][(((4 + q) ^ (ln & 7)) << 3)];
    short8 b11 = *(const short8*)&B_lds[w][ln + 16][(((4 + q) ^ (ln & 7)) << 3)];

    floatx4 acc0 = {0.f, 0.f, 0.f, 0.f}, acc1 = {0.f, 0.f, 0.f, 0.f};
    acc0 = __builtin_amdgcn_mfma_f32_16x16x32_bf16(a0, b00, acc0, 0, 0, 0);
    acc1 = __builtin_amdgcn_mfma_f32_16x16x32_bf16(a0, b01, acc1, 0, 0, 0);
    acc0 = __builtin_amdgcn_mfma_f32_16x16x32_bf16(a1, b10, acc0, 0, 0, 0);
    acc1 = __builtin_amdgcn_mfma_f32_16x16x32_bf16(a1, b11, acc1, 0, 0, 0);

    // epilogue: elementwise W . M once per wave.
    // C/D: col = lane&15 (=n), row = (lane>>4)*4 + reg  (m89-verified)
    float p = 0.0f;
#pragma unroll
    for (int i = 0; i < 4; ++i) {
        int row = q * 4 + i;
        p += acc0[i] * W2r[row * 32 + ln] + acc1[i] * W2r[row * 32 + 16 + ln];
    }
#pragma unroll
    for (int off = 32; off > 0; off >>= 1)
        p += __shfl_down(p, off, 64);

    if (l == 0)
        atomicAdd(partial + (blockIdx.x & 63) * 16, p);
}

__global__ void final_kernel(const float* __restrict__ partial,
                             float* __restrict__ out) {
    int t = threadIdx.x;  // 64
    float v = partial[t * 16];
#pragma unroll
    for (int off = 32; off > 0; off >>= 1)
        v += __shfl_down(v, off, 64);
    if (t == 0) out[0] = v;
}

// Fallback (ws too small for bf16 table): per-edge f32 contraction.
__global__ __launch_bounds__(256, 6) void edge_kernel_f32(
    const float* __restrict__ X, const float* __restrict__ EV,
    const int* __restrict__ SRC, const float* __restrict__ W2r,
    const float* __restrict__ W1s, float* __restrict__ partial, int E)
{
    int tid = threadIdx.x;
    int e = blockIdx.x * 256 + tid;
    float contrib = 0.0f;
    if (e < E) {
        int si = SRC[e];
        const float4* xp = (const float4*)(X + (size_t)si * 32);
        float4 x[8];
#pragma unroll
        for (int k = 0; k < 8; ++k) x[k] = xp[k];
        float ex = EV[3 * e], ey = EV[3 * e + 1], ez = EV[3 * e + 2];
        float r = sqrtf(ex * ex + ey * ey + ez * ez);
        float ir = 1.0f / r;
        float ux = ex * ir, uy = ey * ir, uz = ez * ir;
        float U = ux + uy + uz;
        const float inv_step = 11.0f / 3.0f;
        float qq = r * inv_step;
        int qi = (int)floorf(qq);
        int ia = qi - 1, ib = qi;
        float diffa = qq - (float)(ia + 1), diffb = qq - (float)(ib + 1);
        float dena = 1.0f - diffa * diffa, denb = 1.0f - diffb * diffb;
        float fa = ((ia >= 0) & (ia < NB)) ? 1.14136f * __expf(2.0f - 2.0f / dena) : 0.0f;
        float fb = ((ib >= 0) & (ib < NB)) ? 1.14136f * __expf(2.0f - 2.0f / denb) : 0.0f;
        const float* ra = W1s + min(max(ia, 0), NB - 1) * HID;
        const float* rb = W1s + min(max(ib, 0), NB - 1) * HID;
        float h[HID];
#pragma unroll
        for (int j = 0; j < HID; ++j) {
            float a = fa * ra[j] + fb * rb[j];
            h[j] = (a > 0.0f) ? a : 0.0f;
        }
        float s[8] = {x[0].x, x[0].y, x[0].z, x[0].w, x[1].x, x[1].y, x[1].z, x[1].w};
        float vv[24];
#pragma unroll
        for (int k = 0; k < 6; ++k) {
            vv[4 * k + 0] = x[2 + k].x; vv[4 * k + 1] = x[2 + k].y;
            vv[4 * k + 2] = x[2 + k].z; vv[4 * k + 3] = x[2 + k].w;
        }
        float d[8], V[8];
#pragma unroll
        for (int u = 0; u < 8; ++u) {
            float vx = vv[3 * u], vy = vv[3 * u + 1], vz = vv[3 * u + 2];
            d[u] = vx * ux + vy * uy + vz * uz;
            V[u] = vx + vy + vz;
        }
        float acc = 0.0f;
#pragma unroll
        for (int j = 0; j < HID; ++j) {
            const float* wt = W2r + j * 32;
            float A = 0, B = 0, C = 0, D = 0;
#pragma unroll
            for (int u = 0; u < 8; ++u) {
                A += wt[u] * s[u]; B += wt[8 + u] * d[u];
                C += wt[16 + u] * s[u]; D += wt[24 + u] * V[u];
            }
            acc += h[j] * (A + B + U * C + D);
        }
        contrib = acc;
    }
#pragma unroll
    for (int off = 32; off > 0; off >>= 1)
        contrib += __shfl_down(contrib, off, 64);
    if ((tid & 63) == 0)
        atomicAdd(partial + (blockIdx.x & 63) * 16, contrib);
}

extern "C" void kernel_launch(void* const* d_in, const int* in_sizes, int n_in,
                              void* d_out, int out_size, void* d_ws, size_t ws_size,
                              hipStream_t stream) {
    const float* X   = (const float*)d_in[0];
    const float* EV  = (const float*)d_in[1];
    const float* W1  = (const float*)d_in[2];
    const float* W2  = (const float*)d_in[3];
    const int*   SRC = (const int*)d_in[4];
    int E = in_sizes[4];
    int N = in_sizes[0] / 32;

    float* ws      = (float*)d_ws;
    float* out     = (float*)d_out;
    float* partial = ws + 672;

    size_t xb_off = 8192;
    size_t need   = xb_off + (size_t)N * 64;
    int eblocks = (E + 255) / 256;
    if (ws_size >= need) {
        unsigned* Xb = (unsigned*)((char*)d_ws + xb_off);
        int nPack = N * 16;
        conv_prep_kernel<<<(nPack + 255) / 256, 256, 0, stream>>>(X, Xb, nPack, W1, W2, ws);
        edge_kernel<<<eblocks, 256, 0, stream>>>(Xb, EV, SRC, ws, ws + 512, partial, E);
    } else {
        conv_prep_kernel<<<1, 256, 0, stream>>>(X, (unsigned*)nullptr, 0, W1, W2, ws);
        edge_kernel_f32<<<eblocks, 256, 0, stream>>>(X, EV, SRC, ws, ws + 512, partial, E);
    }
    final_kernel<<<1, 64, 0, stream>>>(partial, out);
}